// Round 4
// baseline (392.677 us; speedup 1.0000x reference)
//
#include <hip/hip_runtime.h>

// Problem constants (reference: B,T,D,O = 16,1024,1024,10; T==D required)
#define BB 16
#define TT 1024
#define DD 1024
#define OO 10
#define ROWS 64
#define MAGIC 0x13579BDFu

// ---------------------------------------------------------------------------
// R17 (this): single cooperative kernel, X tile register-persistent across
// BOTH gemms. Rationale: pass2 (X from L3) ran the same 18.6us as pass1 (X
// from HBM) -> per-pass rate is pinned at ~3.4 TB/s regardless of source, so
// the remaining lever is VOLUME: read X once (64 MB) instead of twice.
// Per thread: 4 rows x 8 float4 chunks = 128 VGPRs persistent; phase A
// (scores->u) and phase B (out = X.u/Z) both consume them. Cross-block u
// visibility within a batch (16 blocks) via flags in d_ws (re-poisoned every
// iteration -> self-resetting) + device-scope atomics + __threadfence. NOT
// grid.sync (R15: ~45us). hipLaunchCooperativeKernel used ONLY for the
// co-residency guarantee (no-deadlock); proven to work under graph capture
// in R15. Fallback: proven R16 two-kernel path if coop launch is rejected.
//
// Measured context: 2x41us 256MiB ws poison fills are UNCONDITIONAL -> 82us
// harness floor; ~37us gemm addressable. Per-wave geometry everywhere is the
// proven R5/R10 body (8-lane groups, 128B slices, broadcast float4 operand
// reads from LDS, 3-level shfl + LDS cross-wave combine, max-free softmax);
// FMA order preserved bit-for-bit vs R16.
//
// Refuted (do not retry): occupancy-hint bounds (R2 spill), per-chunk LDS
// staging barriers (R6), grid.sync fusion (R8/R15), per-block softmax fold
// (R9), non-temporal X loads (R11), depth-4 prefetch (R12), ROWS=32 8-wave
// split (R13), 16-lane/256B chunks (R14), ws-avoidance (R15: fills stay).
// ---------------------------------------------------------------------------
__global__ __launch_bounds__(512) void fused_persist(
    const float* __restrict__ X,     // (B,T,D)
    const float* __restrict__ W,     // (O,D)
    const float* __restrict__ bias,  // (O)
    float* __restrict__ out,         // (B,O,T)
    float* __restrict__ u,           // ws: (B,O,T) intermediate
    unsigned* __restrict__ flags)    // ws: [BB][16] batch-local sync flags
{
    __shared__ float4 sW4[OO * 256];      // 40 KB: W (phase A), u-slab (phase B)
    __shared__ float  part[4][ROWS][OO];  // 10 KB
    __shared__ float  zred[OO];

    const int b   = blockIdx.y;
    const int t0  = blockIdx.x * ROWS;
    const int tid = threadIdx.x;          // 0..511

    // ---- stage W -> LDS ----
    {
        const float4* src = (const float4*)W;
#pragma unroll
        for (int c = 0; c < 5; ++c)
            sW4[c * 512 + tid] = src[c * 512 + tid];
    }
    __syncthreads();

    const int wv8  = tid >> 6;       // wave 0..7
    const int w    = wv8 & 3;        // d quarter
    const int half = wv8 >> 2;       // row half
    const int lane = tid & 63;
    const int l    = lane & 7;       // d-slice within row
    const int g    = lane >> 3;      // row group 0..7
    const int dofs = w * 256 + l * 4;
    const int rb   = half * 32;

    const float* xp[4];
#pragma unroll
    for (int j = 0; j < 4; ++j)
        xp[j] = X + ((size_t)b * TT + t0 + rb + g + 8 * j) * DD + dofs;
    const float* sWl = (const float*)sW4 + dofs;

    // ---- load persistent X tile: 4 rows x 8 chunks = 32 float4 = 128 VGPR.
    // Issue c-major so the phase-A c-loop consumes in arrival order
    // (incremental vmcnt waits; 32 loads in flight = max MLP).
    float4 xr[8][4];
#pragma unroll
    for (int c = 0; c < 8; ++c)
#pragma unroll
        for (int j = 0; j < 4; ++j)
            xr[c][j] = *(const float4*)(xp[j] + c * 32);

    float acc[4][OO];
#pragma unroll
    for (int j = 0; j < 4; ++j)
#pragma unroll
        for (int o = 0; o < OO; ++o) acc[j][o] = 0.f;

    // ---- phase A: scores = X.W^T (identical FMA order to R16) ----
#pragma unroll
    for (int c = 0; c < 8; ++c) {
        const float* wp = sWl + c * 32;
#pragma unroll
        for (int o = 0; o < OO; ++o) {
            const float4 wv = *(const float4*)(wp + o * DD);
#pragma unroll
            for (int j = 0; j < 4; ++j)
                acc[j][o] += xr[c][j].x * wv.x + xr[c][j].y * wv.y +
                             xr[c][j].z * wv.z + xr[c][j].w * wv.w;
        }
    }

    // cross-wave combine
#pragma unroll
    for (int j = 0; j < 4; ++j) {
#pragma unroll
        for (int o = 0; o < OO; ++o) {
            float v = acc[j][o];
            v += __shfl_down(v, 4, 8);
            v += __shfl_down(v, 2, 8);
            v += __shfl_down(v, 1, 8);
            if (l == 0) part[w][rb + j * 8 + g][o] = v;
        }
    }
    __syncthreads();

    // epilogue A: u = exp((dot + bias)/O)
    for (int idx = tid; idx < ROWS * OO; idx += 512) {
        const int row = idx / OO;
        const int o   = idx % OO;
        float v = part[0][row][o] + part[1][row][o] +
                  part[2][row][o] + part[3][row][o];
        u[((size_t)b * OO + o) * TT + (t0 + row)] =
            __expf((v + bias[o]) * (1.0f / OO));
    }

    // ---- publish u, batch-local sync (16 blocks per batch) ----
    __threadfence();                 // u stores -> device scope
    __syncthreads();
    if (tid == 0)
        atomicExch(&flags[b * 16 + blockIdx.x], MAGIC);
    if (tid < 16) {
        while (atomicOr(&flags[b * 16 + tid], 0u) != MAGIC)
            __builtin_amdgcn_s_sleep(8);
    }
    __syncthreads();                 // all 16 flags seen -> whole block released
    __threadfence();                 // acquire side

    // ---- stage u slab (40 KB) -> LDS, overwriting W ----
    {
        const float4* src = (const float4*)(u + (size_t)b * OO * TT);
#pragma unroll
        for (int c = 0; c < 5; ++c)
            sW4[c * 512 + tid] = src[c * 512 + tid];
    }
    __syncthreads();

    // Z[b,o] = sum_t u (from slab). Wave wv8 handles o = wv8 + 8k.
#pragma unroll
    for (int k = 0; k < 2; ++k) {
        const int o = wv8 + 8 * k;
        if (o < OO) {
            float s = 0.f;
#pragma unroll
            for (int q = 0; q < 4; ++q) {
                const float4 v = sW4[o * 256 + lane * 4 + q];
                s += v.x + v.y + v.z + v.w;
            }
#pragma unroll
            for (int off = 32; off > 0; off >>= 1)
                s += __shfl_down(s, off, 64);
            if (lane == 0) zred[o] = s;
        }
    }

    // ---- phase B: out = X.u / Z, X from registers (zero new X traffic) ----
#pragma unroll
    for (int j = 0; j < 4; ++j)
#pragma unroll
        for (int o = 0; o < OO; ++o) acc[j][o] = 0.f;

#pragma unroll
    for (int c = 0; c < 8; ++c) {
        const float* wp = sWl + c * 32;
#pragma unroll
        for (int o = 0; o < OO; ++o) {
            const float4 wv = *(const float4*)(wp + o * DD);
#pragma unroll
            for (int j = 0; j < 4; ++j)
                acc[j][o] += xr[c][j].x * wv.x + xr[c][j].y * wv.y +
                             xr[c][j].z * wv.z + xr[c][j].w * wv.w;
        }
    }

#pragma unroll
    for (int j = 0; j < 4; ++j) {
#pragma unroll
        for (int o = 0; o < OO; ++o) {
            float v = acc[j][o];
            v += __shfl_down(v, 4, 8);
            v += __shfl_down(v, 2, 8);
            v += __shfl_down(v, 1, 8);
            if (l == 0) part[w][rb + j * 8 + g][o] = v;
        }
    }
    __syncthreads();

    for (int idx = tid; idx < ROWS * OO; idx += 512) {
        const int row = idx / OO;
        const int o   = idx % OO;
        float v = part[0][row][o] + part[1][row][o] +
                  part[2][row][o] + part[3][row][o];
        out[((size_t)b * OO + o) * TT + (t0 + row)] = v / zred[o];
    }
}

// ---------------------------------------------------------------------------
// Fallback: proven R16 two-kernel path (119.4 us), used if coop launch fails.
// ---------------------------------------------------------------------------
template <bool FIRST>
__global__ __launch_bounds__(512) void gemm10_kernel(
    const float* __restrict__ X,
    const float* __restrict__ Wt,
    const float* __restrict__ bias,
    float* __restrict__ Y)
{
    __shared__ float4 sW4[OO * 256];
    __shared__ float  part[4][ROWS][OO];
    __shared__ float  zred[OO];

    const int b   = blockIdx.y;
    const int t0  = blockIdx.x * ROWS;
    const int tid = threadIdx.x;

    {
        const float4* src = (const float4*)(Wt + (FIRST ? 0 : (size_t)b * OO * TT));
#pragma unroll
        for (int c = 0; c < 5; ++c)
            sW4[c * 512 + tid] = src[c * 512 + tid];
    }
    __syncthreads();

    const int wv8  = tid >> 6;
    const int w    = wv8 & 3;
    const int half = wv8 >> 2;
    const int lane = tid & 63;
    const int l    = lane & 7;
    const int g    = lane >> 3;
    const int dofs = w * 256 + l * 4;
    const int rb   = half * 32;

    if (!FIRST) {
#pragma unroll
        for (int k = 0; k < 2; ++k) {
            const int o = wv8 + 8 * k;
            if (o < OO) {
                float s = 0.f;
#pragma unroll
                for (int q = 0; q < 4; ++q) {
                    const float4 v = sW4[o * 256 + lane * 4 + q];
                    s += v.x + v.y + v.z + v.w;
                }
#pragma unroll
                for (int off = 32; off > 0; off >>= 1)
                    s += __shfl_down(s, off, 64);
                if (lane == 0) zred[o] = s;
            }
        }
    }

    const float* xp[4];
#pragma unroll
    for (int j = 0; j < 4; ++j)
        xp[j] = X + ((size_t)b * TT + t0 + rb + g + 8 * j) * DD + dofs;
    const float* sWl = (const float*)sW4 + dofs;

    float acc[4][OO];
#pragma unroll
    for (int j = 0; j < 4; ++j)
#pragma unroll
        for (int o = 0; o < OO; ++o) acc[j][o] = 0.f;

    float4 x0[4], x1[4];
#pragma unroll
    for (int j = 0; j < 4; ++j) {
        x0[j] = *(const float4*)(xp[j]);
        x1[j] = *(const float4*)(xp[j] + 32);
    }

#pragma unroll 1
    for (int it = 0; it < 8; it += 2) {
        float4 c0[4];
#pragma unroll
        for (int j = 0; j < 4; ++j) c0[j] = x0[j];
        if (it < 6) {
#pragma unroll
            for (int j = 0; j < 4; ++j)
                x0[j] = *(const float4*)(xp[j] + (it + 2) * 32);
        }
        {
            const float* wp = sWl + it * 32;
#pragma unroll
            for (int o = 0; o < OO; ++o) {
                const float4 wv = *(const float4*)(wp + o * DD);
#pragma unroll
                for (int j = 0; j < 4; ++j)
                    acc[j][o] += c0[j].x * wv.x + c0[j].y * wv.y +
                                 c0[j].z * wv.z + c0[j].w * wv.w;
            }
        }
#pragma unroll
        for (int j = 0; j < 4; ++j) c0[j] = x1[j];
        if (it < 5) {
#pragma unroll
            for (int j = 0; j < 4; ++j)
                x1[j] = *(const float4*)(xp[j] + (it + 3) * 32);
        }
        {
            const float* wp = sWl + (it + 1) * 32;
#pragma unroll
            for (int o = 0; o < OO; ++o) {
                const float4 wv = *(const float4*)(wp + o * DD);
#pragma unroll
                for (int j = 0; j < 4; ++j)
                    acc[j][o] += c0[j].x * wv.x + c0[j].y * wv.y +
                                 c0[j].z * wv.z + c0[j].w * wv.w;
            }
        }
    }

#pragma unroll
    for (int j = 0; j < 4; ++j) {
#pragma unroll
        for (int o = 0; o < OO; ++o) {
            float v = acc[j][o];
            v += __shfl_down(v, 4, 8);
            v += __shfl_down(v, 2, 8);
            v += __shfl_down(v, 1, 8);
            if (l == 0) part[w][rb + j * 8 + g][o] = v;
        }
    }
    __syncthreads();

    for (int idx = tid; idx < ROWS * OO; idx += 512) {
        const int row = idx / OO;
        const int o   = idx % OO;
        float v = part[0][row][o] + part[1][row][o] +
                  part[2][row][o] + part[3][row][o];
        if (FIRST) {
            Y[((size_t)b * OO + o) * TT + (t0 + row)] =
                __expf((v + bias[o]) * (1.0f / OO));
        } else {
            Y[((size_t)b * OO + o) * TT + (t0 + row)] = v / zred[o];
        }
    }
}

extern "C" void kernel_launch(void* const* d_in, const int* in_sizes, int n_in,
                              void* d_out, int out_size, void* d_ws, size_t ws_size,
                              hipStream_t stream)
{
    const float* logits = (const float*)d_in[0];
    // d_in[1] = decision — unused by the forward math
    const float* W    = (const float*)d_in[2];
    const float* bias = (const float*)d_in[3];
    float* out = (float*)d_out;

    unsigned* flags = (unsigned*)d_ws;              // 256 words (poisoned/iter)
    float*    u     = (float*)d_ws + 1024;          // 4 KB offset; 655 KB slab

    dim3 grid(TT / ROWS, BB);       // (16,16) = 256 blocks = 1/CU
    dim3 block(512);

    void* args[] = { (void*)&logits, (void*)&W, (void*)&bias,
                     (void*)&out, (void*)&u, (void*)&flags };
    hipError_t err = hipLaunchCooperativeKernel(
        (const void*)fused_persist, grid, block, args, 0, stream);

    if (err != hipSuccess) {
        (void)hipGetLastError();
        gemm10_kernel<true><<<grid, block, 0, stream>>>(logits, W, bias, u);
        gemm10_kernel<false><<<grid, block, 0, stream>>>(logits, u, nullptr, out);
    }
}